// Round 1
// baseline (603.522 us; speedup 1.0000x reference)
//
#include <hip/hip_runtime.h>
#include <cstddef>

typedef unsigned short u16;
typedef __attribute__((ext_vector_type(8))) short bf8;   // 8 x bf16 (4 VGPRs)
typedef __attribute__((ext_vector_type(4))) float f4;
typedef __attribute__((ext_vector_type(4))) unsigned short us4;

#define NATOMS 11776
#define NBLK   368

__device__ __forceinline__ u16 f2b(float x){
  union { float f; unsigned u; } v; v.f = x;
  unsigned r = v.u + 0x7fffu + ((v.u >> 16) & 1u);
  return (u16)(r >> 16);
}
__device__ __forceinline__ f4 f4zero(){ f4 z = {0.f,0.f,0.f,0.f}; return z; }
__device__ __forceinline__ f4 mfma16(bf8 a, bf8 b, f4 c){
  return __builtin_amdgcn_mfma_f32_16x16x32_bf16(a, b, c, 0, 0, 0);
}
__device__ __forceinline__ int iclamp(int v, int lo, int hi){ return v < lo ? lo : (v > hi ? hi : v); }

// ---------------------------------------------------------------- convert fp32 -> bf16
struct CvtArgs {
  const float* src[13];
  u16* dst[13];
  int n4[13];
};

__global__ __launch_bounds__(256) void k_convert(CvtArgs a){
  int stride = gridDim.x * 256;
  int tid = blockIdx.x * 256 + threadIdx.x;
  for (int s = 0; s < 13; ++s){
    const float4* src = (const float4*)a.src[s];
    us4* dst = (us4*)a.dst[s];
    int n = a.n4[s];
    for (int i = tid; i < n; i += stride){
      float4 v = src[i];
      us4 o;
      o.x = f2b(v.x); o.y = f2b(v.y); o.z = f2b(v.z); o.w = f2b(v.w);
      dst[i] = o;
    }
  }
}

// ---------------------------------------------------------------- generic 16-row MFMA strip GEMM
// WG = 256 threads (4 waves). Computes C[16][N] = A16[16][K] @ W[N][K]^T into LDS (f32).
// A/B fragment pattern: lane&15 selects row (A) / col-of-W (B); (lane>>4)*8+j selects k.
// Identical k-pattern on both operands => any HW k-permutation cancels.
template<int N, int K>
__device__ __forceinline__ void gemm_strip(const u16* __restrict__ A, const u16* __restrict__ W, float* L){
  constexpr int CPW = N / 4;       // cols per wave
  constexpr int T = CPW / 16;      // 16x16 tiles per wave
  const int lane = threadIdx.x & 63;
  const int wave = threadIdx.x >> 6;
  const int rr = lane & 15, grp = lane >> 4;
  f4 acc[T];
#pragma unroll
  for (int t = 0; t < T; ++t) acc[t] = f4zero();
#pragma unroll
  for (int kc = 0; kc < K / 32; ++kc){
    bf8 af = *(const bf8*)(A + rr * K + kc * 32 + grp * 8);
#pragma unroll
    for (int t = 0; t < T; ++t){
      const u16* wp = W + (size_t)(wave * CPW + t * 16 + rr) * K + kc * 32 + grp * 8;
      acc[t] = mfma16(af, *(const bf8*)wp, acc[t]);
    }
  }
  // C/D layout (verified): col = lane&15, row = (lane>>4)*4 + reg
#pragma unroll
  for (int t = 0; t < T; ++t)
#pragma unroll
    for (int r = 0; r < 4; ++r)
      L[(grp * 4 + r) * N + wave * CPW + t * 16 + rr] = acc[t][r];
}

// plain f32 output
template<int N, int K>
__global__ __launch_bounds__(256) void k_gemm_f32(const u16* __restrict__ A, const u16* __restrict__ W,
                                                  float* __restrict__ out){
  __shared__ float L[16 * N];
  const int strip = blockIdx.x;
  gemm_strip<N, K>(A + (size_t)strip * 16 * K, W, L);
  __syncthreads();
  const size_t base = (size_t)strip * 16 * N;
  for (int i = threadIdx.x; i < 16 * N; i += 256) out[base + i] = L[i];
}

// x = sigmoid(gb[:,:128]) * lnA + gb[:,128:]  (adaLN)  -> bf16
__global__ __launch_bounds__(256) void k_gemm_x(const u16* __restrict__ A, const u16* __restrict__ W,
                                                const float* __restrict__ lnA, u16* __restrict__ xout){
  __shared__ float L[16 * 256];
  const int strip = blockIdx.x;
  gemm_strip<256, 128>(A + (size_t)strip * 2048, W, L);
  __syncthreads();
  for (int i = threadIdx.x; i < 16 * 128; i += 256){
    int r = i >> 7, c = i & 127;
    float g1 = L[r * 256 + c], g2 = L[r * 256 + 128 + c];
    float s = 1.f / (1.f + __expf(-g1));
    size_t idx = (size_t)(strip * 16 + r) * 128 + c;
    xout[idx] = f2b(s * lnA[idx] + g2);
  }
}

// qkv with q-bias + score-scale folded into q  -> bf16
__global__ __launch_bounds__(256) void k_gemm_qkv(const u16* __restrict__ A, const u16* __restrict__ W,
                                                  const float* __restrict__ qb, u16* __restrict__ out){
  __shared__ float L[16 * 384];
  const int strip = blockIdx.x;
  gemm_strip<384, 128>(A + (size_t)strip * 2048, W, L);
  __syncthreads();
  const float scale = 0.17677669529663687f; // 1/sqrt(32)
  for (int i = threadIdx.x; i < 16 * 384; i += 256){
    int r = i / 384, c = i - r * 384;
    float v = L[i];
    if (c < 128) v = (v + qb[c]) * scale;
    out[(size_t)(strip * 16 + r) * 384 + c] = f2b(v);
  }
}

// gate = sigmoid(gemm + gate_b)  -> f32
__global__ __launch_bounds__(256) void k_gemm_gate(const u16* __restrict__ A, const u16* __restrict__ W,
                                                   const float* __restrict__ gb, float* __restrict__ gate){
  __shared__ float L[16 * 128];
  const int strip = blockIdx.x;
  gemm_strip<128, 128>(A + (size_t)strip * 2048, W, L);
  __syncthreads();
  for (int i = threadIdx.x; i < 2048; i += 256){
    int c = i & 127;
    gate[(size_t)strip * 2048 + i] = 1.f / (1.f + __expf(-(L[i] + gb[c])));
  }
}

// relu epilogue (atom_out = relu(a @ W_tok^T)) -> f32
__global__ __launch_bounds__(256) void k_gemm_relu(const u16* __restrict__ A, const u16* __restrict__ W,
                                                   float* __restrict__ out){
  __shared__ float L[16 * 384];
  const int strip = blockIdx.x;
  gemm_strip<384, 128>(A + (size_t)strip * 2048, W, L);
  __syncthreads();
  const size_t base = (size_t)strip * 16 * 384;
  for (int i = threadIdx.x; i < 16 * 384; i += 256) out[base + i] = fmaxf(L[i], 0.f);
}

// GLU: g = silu(ab[:,:256]) * ab[:,256:]  -> bf16
__global__ __launch_bounds__(256) void k_gemm_glu(const u16* __restrict__ A, const u16* __restrict__ W,
                                                  u16* __restrict__ g){
  __shared__ float L[16 * 512];
  const int strip = blockIdx.x;
  gemm_strip<512, 128>(A + (size_t)strip * 2048, W, L);
  __syncthreads();
  for (int i = threadIdx.x; i < 16 * 256; i += 256){
    int r = i >> 8, c = i & 255;
    float ab1 = L[r * 512 + c], ab2 = L[r * 512 + 256 + c];
    float silu = ab1 / (1.f + __expf(-ab1));
    g[(size_t)(strip * 16 + r) * 256 + c] = f2b(silu * ab2);
  }
}

// h-gemm (K=256) + gated residual a += gate*h, then row-LN -> lnA
__global__ __launch_bounds__(256) void k_gemm_tb(const u16* __restrict__ A, const u16* __restrict__ W,
                                                 const float* __restrict__ gate, float* __restrict__ a,
                                                 u16* __restrict__ a_bf, float* __restrict__ lnA){
  __shared__ float L[16 * 128];
  const int strip = blockIdx.x;
  gemm_strip<128, 256>(A + (size_t)strip * 16 * 256, W, L);
  __syncthreads();
  for (int i = threadIdx.x; i < 2048; i += 256){
    size_t idx = (size_t)strip * 2048 + i;
    float v = a[idx] + gate[idx] * L[i];
    a[idx] = v;
    a_bf[idx] = f2b(v);
    L[i] = v;
  }
  __syncthreads();
  // row LN: 16 rows x 16 threads, 8 elems each; shfl groups of 16 aligned within wave
  int r = threadIdx.x >> 4, s = threadIdx.x & 15;
  float sum = 0.f, sq = 0.f;
#pragma unroll
  for (int j = 0; j < 8; ++j){ float v = L[r * 128 + s * 8 + j]; sum += v; sq += v * v; }
#pragma unroll
  for (int m = 1; m < 16; m <<= 1){ sum += __shfl_xor(sum, m); sq += __shfl_xor(sq, m); }
  float mu = sum * (1.f / 128.f);
  float var = sq * (1.f / 128.f) - mu * mu;
  float rs = rsqrtf(var + 1e-5f);
#pragma unroll
  for (int j = 0; j < 8; ++j){
    int c = s * 8 + j;
    lnA[(size_t)(strip * 16 + r) * 128 + c] = (L[r * 128 + c] - mu) * rs;
  }
}

// ---------------------------------------------------------------- LN(c) + relu -> ph/pw projections
// one wave per row
__global__ __launch_bounds__(256) void k_ln_phpw(const float* __restrict__ c, float* __restrict__ lnA,
                                                 u16* __restrict__ slnb, const float* __restrict__ Wph,
                                                 const float* __restrict__ Wpw, float* __restrict__ ph,
                                                 float* __restrict__ pw){
  __shared__ float rs[4][128];
  const int wave = threadIdx.x >> 6, lane = threadIdx.x & 63;
  const int row = blockIdx.x * 4 + wave;
  const float* cr = c + (size_t)row * 128;
  float2 v = *(const float2*)(cr + lane * 2);
  float sum = v.x + v.y, sq = v.x * v.x + v.y * v.y;
#pragma unroll
  for (int m = 1; m < 64; m <<= 1){ sum += __shfl_xor(sum, m); sq += __shfl_xor(sq, m); }
  float mu = sum * (1.f / 128.f);
  float var = sq * (1.f / 128.f) - mu * mu;
  float r = rsqrtf(var + 1e-5f);
  float s0 = (v.x - mu) * r, s1 = (v.y - mu) * r;
  size_t base = (size_t)row * 128 + lane * 2;
  lnA[base] = s0; lnA[base + 1] = s1;
  slnb[base] = f2b(s0); slnb[base + 1] = f2b(s1);
  rs[wave][lane * 2] = fmaxf(s0, 0.f); rs[wave][lane * 2 + 1] = fmaxf(s1, 0.f);
  __syncthreads();
  int h = lane & 15, part = lane >> 4;
  float acch = 0.f, accw = 0.f;
#pragma unroll
  for (int k = 0; k < 32; ++k){
    int kk = part * 32 + k;
    float rv = rs[wave][kk];
    acch += rv * Wph[h * 128 + kk];
    accw += rv * Wpw[h * 128 + kk];
  }
  acch += __shfl_xor(acch, 16); acch += __shfl_xor(acch, 32);
  accw += __shfl_xor(accw, 16); accw += __shfl_xor(accw, 32);
  if (lane < 16){
    ph[(size_t)row * 16 + h] = acch;
    pw[(size_t)row * 16 + h] = accw;
  }
}

// ---------------------------------------------------------------- pair-bias MLP -> bias[b][h][q][k] (pb + neg-mask)
__global__ __launch_bounds__(256) void k_pb(const float* __restrict__ ph, const float* __restrict__ pw,
                                            const float* __restrict__ W1, const float* __restrict__ W2,
                                            const float* __restrict__ lnw, const float* __restrict__ lnb,
                                            const float* __restrict__ pbw, float* __restrict__ bias){
  __shared__ float sW1[256], sW2[256], slnw[16], slnb_[16], spbw[64];
  const int t = threadIdx.x, b = blockIdx.x;
  sW1[t & 255] = W1[t & 255];
  sW2[t & 255] = W2[t & 255];
  if (t < 16){ slnw[t] = lnw[t]; slnb_[t] = lnb[t]; }
  if (t < 64) spbw[t] = pbw[t];
  __syncthreads();
  const int k = t & 127, qh = t >> 7;
  const int win = b * 32 + k - 48;
  const bool valid = (win >= 0) && (win < NATOMS);
  const int ka = iclamp(win, 0, NATOMS - 1);
  float pwv[16];
#pragma unroll
  for (int cc = 0; cc < 16; ++cc) pwv[cc] = pw[(size_t)ka * 16 + cc];
  const float negv = valid ? 0.f : -1e9f;
  for (int i = 0; i < 16; ++i){
    int q = qh * 16 + i;
    int qa = b * 32 + q;
    float p[16];
#pragma unroll
    for (int cc = 0; cc < 16; ++cc) p[cc] = ph[(size_t)qa * 16 + cc] + pwv[cc];
    float m[16];
#pragma unroll
    for (int o = 0; o < 16; ++o){
      float s = 0.f;
#pragma unroll
      for (int cc = 0; cc < 16; ++cc) s += fmaxf(p[cc], 0.f) * sW1[o * 16 + cc];
      m[o] = fmaxf(s, 0.f);
    }
#pragma unroll
    for (int cc = 0; cc < 16; ++cc){
      float s = 0.f;
#pragma unroll
      for (int o = 0; o < 16; ++o) s += m[o] * sW2[cc * 16 + o];
      p[cc] += s;
    }
    float mu = 0.f;
#pragma unroll
    for (int cc = 0; cc < 16; ++cc) mu += p[cc];
    mu *= (1.f / 16.f);
    float var = 0.f;
#pragma unroll
    for (int cc = 0; cc < 16; ++cc){ float d = p[cc] - mu; var += d * d; }
    var *= (1.f / 16.f);
    float rr = rsqrtf(var + 1e-5f);
    float ln[16];
#pragma unroll
    for (int cc = 0; cc < 16; ++cc) ln[cc] = (p[cc] - mu) * rr * slnw[cc] + slnb_[cc];
#pragma unroll
    for (int hh = 0; hh < 4; ++hh){
      float s = 0.f;
#pragma unroll
      for (int cc = 0; cc < 16; ++cc) s += ln[cc] * spbw[hh * 16 + cc];
      bias[((size_t)((b * 4 + hh) * 32) + q) * 128 + k] = s + negv;
    }
  }
}

// ---------------------------------------------------------------- block attention + out-proj + residual + row-LN
__global__ __launch_bounds__(256) void k_attn(const u16* __restrict__ qkv, const float* __restrict__ bias,
                                              const u16* __restrict__ outw, const float* __restrict__ outb,
                                              float* __restrict__ a, float* __restrict__ lnA){
  __shared__ u16 VT[128][136];      // V transposed: [dim][k-atom]
  __shared__ u16 P[4][32 * 136];    // softmax probs per head
  __shared__ u16 O[32][136];        // attention output (q x 128)
  __shared__ float aL[32][128];     // updated residual rows for LN
  const int t = threadIdx.x;
  const int lane = t & 63, wave = t >> 6;
  const int b = blockIdx.x;
  const int rr = lane & 15, grp = lane >> 4;

  // stage V transposed
  for (int i = 0; i < 8; ++i){
    int s = t + 256 * i;
    int ka = s & 127, d0 = (s >> 7) * 8;
    int win = b * 32 + ka - 48;
    int src = iclamp(win, 0, NATOMS - 1);
    bf8 v = *(const bf8*)(qkv + (size_t)src * 384 + 256 + d0);
#pragma unroll
    for (int j = 0; j < 8; ++j) VT[d0 + j][ka] = (u16)v[j];
  }
  __syncthreads();

  const int h = wave;
  // S = q @ k^T   (scale pre-folded into q)
  bf8 kfr[8];
#pragma unroll
  for (int kt = 0; kt < 8; ++kt){
    int ka = kt * 16 + rr;
    int win = b * 32 + ka - 48;
    int src = iclamp(win, 0, NATOMS - 1);
    kfr[kt] = *(const bf8*)(qkv + (size_t)src * 384 + 128 + h * 32 + grp * 8);
  }
  f4 S[2][8];
#pragma unroll
  for (int qt = 0; qt < 2; ++qt){
    bf8 qf = *(const bf8*)(qkv + (size_t)(b * 32 + qt * 16 + rr) * 384 + h * 32 + grp * 8);
#pragma unroll
    for (int kt = 0; kt < 8; ++kt){
      S[qt][kt] = f4zero();
      S[qt][kt] = mfma16(qf, kfr[kt], S[qt][kt]);
    }
  }
  // softmax (+bias incl. mask) -> P (bf16 in LDS)
  const float* brow = bias + (size_t)((b * 4 + h) * 32) * 128;
#pragma unroll
  for (int qt = 0; qt < 2; ++qt){
#pragma unroll
    for (int r = 0; r < 4; ++r){
      int q = qt * 16 + grp * 4 + r;
      float vals[8];
      float mx = -1e30f;
#pragma unroll
      for (int kt = 0; kt < 8; ++kt){
        float v = S[qt][kt][r] + brow[q * 128 + kt * 16 + rr];
        vals[kt] = v;
        mx = fmaxf(mx, v);
      }
#pragma unroll
      for (int m = 1; m < 16; m <<= 1) mx = fmaxf(mx, __shfl_xor(mx, m));
      float sum = 0.f;
#pragma unroll
      for (int kt = 0; kt < 8; ++kt){ vals[kt] = __expf(vals[kt] - mx); sum += vals[kt]; }
#pragma unroll
      for (int m = 1; m < 16; m <<= 1) sum += __shfl_xor(sum, m);
      float inv = 1.f / sum;
#pragma unroll
      for (int kt = 0; kt < 8; ++kt)
        P[h][q * 136 + kt * 16 + rr] = f2b(vals[kt] * inv);
    }
  }
  __syncthreads();
  // O = P @ V
  f4 oacc[2][2];
#pragma unroll
  for (int qt = 0; qt < 2; ++qt)
#pragma unroll
    for (int dt = 0; dt < 2; ++dt) oacc[qt][dt] = f4zero();
#pragma unroll
  for (int kc = 0; kc < 4; ++kc){
#pragma unroll
    for (int qt = 0; qt < 2; ++qt){
      bf8 pa = *(const bf8*)(&P[h][(qt * 16 + rr) * 136 + kc * 32 + grp * 8]);
#pragma unroll
      for (int dt = 0; dt < 2; ++dt){
        bf8 vb = *(const bf8*)(&VT[h * 32 + dt * 16 + rr][kc * 32 + grp * 8]);
        oacc[qt][dt] = mfma16(pa, vb, oacc[qt][dt]);
      }
    }
  }
#pragma unroll
  for (int qt = 0; qt < 2; ++qt)
#pragma unroll
    for (int dt = 0; dt < 2; ++dt)
#pragma unroll
      for (int r = 0; r < 4; ++r)
        O[qt * 16 + grp * 4 + r][h * 32 + dt * 16 + rr] = f2b(oacc[qt][dt][r]);
  __syncthreads();
  // out projection + residual
  f4 pacc[2][2];
#pragma unroll
  for (int qt = 0; qt < 2; ++qt)
#pragma unroll
    for (int ct = 0; ct < 2; ++ct) pacc[qt][ct] = f4zero();
#pragma unroll
  for (int kc = 0; kc < 4; ++kc){
    bf8 a0 = *(const bf8*)(&O[rr][kc * 32 + grp * 8]);
    bf8 a1 = *(const bf8*)(&O[16 + rr][kc * 32 + grp * 8]);
#pragma unroll
    for (int ct = 0; ct < 2; ++ct){
      bf8 wf = *(const bf8*)(outw + (size_t)(wave * 32 + ct * 16 + rr) * 128 + kc * 32 + grp * 8);
      pacc[0][ct] = mfma16(a0, wf, pacc[0][ct]);
      pacc[1][ct] = mfma16(a1, wf, pacc[1][ct]);
    }
  }
#pragma unroll
  for (int qt = 0; qt < 2; ++qt)
#pragma unroll
    for (int ct = 0; ct < 2; ++ct)
#pragma unroll
      for (int r = 0; r < 4; ++r){
        int q = qt * 16 + grp * 4 + r;
        int col = wave * 32 + ct * 16 + rr;
        size_t idx = (size_t)(b * 32 + q) * 128 + col;
        float v = a[idx] + pacc[qt][ct][r] + outb[col];
        a[idx] = v;
        aL[q][col] = v;
      }
  __syncthreads();
  // row LN of updated a -> lnA
  {
    int r = t >> 3, s8 = t & 7;
    float sum = 0.f, sq = 0.f;
#pragma unroll
    for (int j = 0; j < 16; ++j){ float v = aL[r][s8 * 16 + j]; sum += v; sq += v * v; }
#pragma unroll
    for (int m = 1; m < 8; m <<= 1){ sum += __shfl_xor(sum, m); sq += __shfl_xor(sq, m); }
    float mu = sum * (1.f / 128.f);
    float var = sq * (1.f / 128.f) - mu * mu;
    float rs = rsqrtf(var + 1e-5f);
#pragma unroll
    for (int j = 0; j < 16; ++j){
      int c = s8 * 16 + j;
      lnA[(size_t)(b * 32 + r) * 128 + c] = (aL[r][c] - mu) * rs;
    }
  }
}

// ---------------------------------------------------------------- segment mean (atoms -> tokens)
__device__ __forceinline__ int lbound(const int* __restrict__ arr, int n, int v){
  int lo = 0, hi = n;
  while (lo < hi){ int mid = (lo + hi) >> 1; if (arr[mid] < v) lo = mid + 1; else hi = mid; }
  return lo;
}

__global__ __launch_bounds__(256) void k_segmean(const float* __restrict__ atom_out,
                                                 const int* __restrict__ a2t, u16* __restrict__ tokbf){
  const int tok = blockIdx.x;
  __shared__ int lo_s, hi_s;
  if (threadIdx.x == 0){
    lo_s = lbound(a2t, NATOMS, tok);
    hi_s = lbound(a2t, NATOMS, tok + 1);
  }
  __syncthreads();
  int lo = lo_s, hi = hi_s;
  float inv = 1.f / fmaxf((float)(hi - lo), 1.f);
  for (int c = threadIdx.x; c < 384; c += 256){
    float s = 0.f;
    for (int aa = lo; aa < hi; ++aa) s += atom_out[(size_t)aa * 384 + c];
    tokbf[(size_t)tok * 384 + c] = f2b(s * inv);
  }
}

// ---------------------------------------------------------------- pair head: tpf@Wp^T + u_i + u_j
__global__ __launch_bounds__(256) void k_pair(const float* __restrict__ tpf, const float* __restrict__ Wp,
                                              const float* __restrict__ u, float* __restrict__ out){
  __shared__ float stpf[32][32];
  const int blk = blockIdx.x;
  const int pair0 = blk * 32;          // 32 (i,j) pairs per block, all same i
  const int t = threadIdx.x;
  for (int idx = t; idx < 1024; idx += 256){
    int pp = idx >> 5, k = idx & 31;
    int p = pair0 + pp;
    stpf[pp][k] = tpf[(size_t)p * 32 + k];
  }
  __syncthreads();
  const int c = t & 127;
  const int half = t >> 7;
  float w[32];
#pragma unroll
  for (int k = 0; k < 32; ++k) w[k] = Wp[c * 32 + k];
  const int i = pair0 >> 9;
  const float ui = u[(size_t)i * 256 + c];
  for (int pp = half * 16; pp < half * 16 + 16; ++pp){
    int p = pair0 + pp;
    int j = p & 511;
    float s = ui + u[(size_t)j * 256 + 128 + c];
#pragma unroll
    for (int k = 0; k < 32; ++k) s += stpf[pp][k] * w[k];
    out[(size_t)p * 128 + c] = s;
  }
}

// ================================================================ host
extern "C" void kernel_launch(void* const* d_in, const int* in_sizes, int n_in,
                              void* d_out, int out_size, void* d_ws, size_t ws_size,
                              hipStream_t stream){
  (void)in_sizes; (void)n_in; (void)out_size; (void)ws_size;
  const float* atom_feats = (const float*)d_in[0];
  const float* tpf        = (const float*)d_in[1];
  const float* W_cond     = (const float*)d_in[2];
  const float* W_ph       = (const float*)d_in[3];
  const float* W_pw       = (const float*)d_in[4];
  const float* W_mlp1     = (const float*)d_in[5];
  const float* W_mlp2     = (const float*)d_in[6];
  const float* pb_ln_w    = (const float*)d_in[7];
  const float* pb_ln_b    = (const float*)d_in[8];
  const float* pb_w       = (const float*)d_in[9];
  const float* sln_w      = (const float*)d_in[10];
  const float* qkv_w      = (const float*)d_in[11];
  const float* q_bias     = (const float*)d_in[12];
  const float* out_w      = (const float*)d_in[13];
  const float* out_b      = (const float*)d_in[14];
  const float* ada_w      = (const float*)d_in[15];
  const float* ta_w       = (const float*)d_in[16];
  const float* tb_w       = (const float*)d_in[17];
  const float* gate_w     = (const float*)d_in[18];
  const float* gate_b     = (const float*)d_in[19];
  const float* W_tok      = (const float*)d_in[20];
  const float* W_trunk    = (const float*)d_in[21];
  const float* W_struct   = (const float*)d_in[22];
  const float* W_pairin   = (const float*)d_in[23];
  const float* W_outer    = (const float*)d_in[24];
  const int*   a2t        = (const int*)d_in[28];

  char* wsb = (char*)d_ws;
  size_t off = 0;
  auto alc = [&](size_t bytes) -> void* {
    void* r = wsb + off;
    off = (off + bytes + 255) & ~(size_t)255;
    return r;
  };

  u16* af_bf     = (u16*)alc((size_t)NATOMS * 128 * 2);
  u16* wcond_bf  = (u16*)alc(16384 * 2);
  u16* sln_bfw   = (u16*)alc(98304 * 2);
  u16* qkv_bfw   = (u16*)alc(147456 * 2);
  u16* out_bfw   = (u16*)alc(49152 * 2);
  u16* ada_bfw   = (u16*)alc(98304 * 2);
  u16* ta_bfw    = (u16*)alc(196608 * 2);
  u16* tb_bfw    = (u16*)alc(98304 * 2);
  u16* gate_bfw  = (u16*)alc(49152 * 2);
  u16* tok_bfw   = (u16*)alc(49152 * 2);
  u16* trunk_bfw = (u16*)alc(147456 * 2);
  u16* struct_bfw= (u16*)alc(147456 * 2);
  u16* outer_bfw = (u16*)alc(98304 * 2);
  float* a_f     = (float*)alc((size_t)NATOMS * 128 * 4);
  float* lnA     = (float*)alc((size_t)NATOMS * 128 * 4);
  u16* sln_bf    = (u16*)alc((size_t)NATOMS * 128 * 2);
  u16* x_bf      = (u16*)alc((size_t)NATOMS * 128 * 2);
  u16* qkv_bf    = (u16*)alc((size_t)NATOMS * 384 * 2);
  u16* g_bf      = (u16*)alc((size_t)NATOMS * 256 * 2);
  float* gate_f  = (float*)alc((size_t)NATOMS * 128 * 4);
  u16* a_bf      = (u16*)alc((size_t)NATOMS * 128 * 2);
  float* ph      = (float*)alc((size_t)NATOMS * 16 * 4);
  float* pw      = (float*)alc((size_t)NATOMS * 16 * 4);
  float* bias    = (float*)alc((size_t)NBLK * 4 * 32 * 128 * 4);
  float* atom_out= bias; // alias: bias dead after layer-2 attention
  u16* tok_bf    = (u16*)alc(512 * 384 * 2);
  float* u_f     = (float*)alc(512 * 256 * 4);

  float* s_trunk  = (float*)d_out;
  float* s_struct = s_trunk + 512 * 384;
  float* pair_out = s_struct + 512 * 384;

  // convert weights + atom_feats to bf16
  CvtArgs ca;
  const float* srcs[13] = {atom_feats, W_cond, sln_w, qkv_w, out_w, ada_w, ta_w, tb_w,
                           gate_w, W_tok, W_trunk, W_struct, W_outer};
  u16* dsts[13] = {af_bf, wcond_bf, sln_bfw, qkv_bfw, out_bfw, ada_bfw, ta_bfw, tb_bfw,
                   gate_bfw, tok_bfw, trunk_bfw, struct_bfw, outer_bfw};
  int n4s[13] = {NATOMS * 128 / 4, 4096, 24576, 36864, 12288, 24576, 49152, 24576,
                 12288, 12288, 36864, 36864, 24576};
  for (int s = 0; s < 13; ++s){ ca.src[s] = srcs[s]; ca.dst[s] = dsts[s]; ca.n4[s] = n4s[s]; }
  k_convert<<<512, 256, 0, stream>>>(ca);

  // c = atom_feats @ W_cond^T  -> a_f
  k_gemm_f32<128, 128><<<736, 256, 0, stream>>>(af_bf, wcond_bf, a_f);
  // s_ln = LN(c) (-> lnA f32 + sln_bf bf16), ph/pw projections
  k_ln_phpw<<<2944, 256, 0, stream>>>(a_f, lnA, sln_bf, W_ph, W_pw, ph, pw);
  // pair-bias MLP -> bias (incl. -1e9 mask)
  k_pb<<<NBLK, 256, 0, stream>>>(ph, pw, W_mlp1, W_mlp2, pb_ln_w, pb_ln_b, pb_w, bias);

  for (int l = 0; l < 3; ++l){
    const u16* slnW  = sln_bfw  + (size_t)l * 256 * 128;
    const u16* qkvW  = qkv_bfw  + (size_t)l * 384 * 128;
    const u16* outW  = out_bfw  + (size_t)l * 128 * 128;
    const u16* adaW  = ada_bfw  + (size_t)l * 256 * 128;
    const u16* taW   = ta_bfw   + (size_t)l * 512 * 128;
    const u16* tbW   = tb_bfw   + (size_t)l * 128 * 256;
    const u16* gateW = gate_bfw + (size_t)l * 128 * 128;
    k_gemm_x<<<736, 256, 0, stream>>>(sln_bf, slnW, lnA, x_bf);
    k_gemm_qkv<<<736, 256, 0, stream>>>(x_bf, qkvW, q_bias + l * 128, qkv_bf);
    k_gemm_gate<<<736, 256, 0, stream>>>(sln_bf, gateW, gate_b + l * 128, gate_f);
    k_attn<<<NBLK, 256, 0, stream>>>(qkv_bf, bias, outW, out_b + l * 128, a_f, lnA);
    k_gemm_x<<<736, 256, 0, stream>>>(sln_bf, adaW, lnA, x_bf);
    k_gemm_glu<<<736, 256, 0, stream>>>(x_bf, taW, g_bf);
    k_gemm_tb<<<736, 256, 0, stream>>>(g_bf, tbW, gate_f, a_f, a_bf, lnA);
  }

  // token head
  k_gemm_relu<<<736, 256, 0, stream>>>(a_bf, tok_bfw, atom_out);
  k_segmean<<<512, 256, 0, stream>>>(atom_out, a2t, tok_bf);
  k_gemm_f32<384, 384><<<32, 256, 0, stream>>>(tok_bf, trunk_bfw, s_trunk);
  k_gemm_f32<384, 384><<<32, 256, 0, stream>>>(tok_bf, struct_bfw, s_struct);
  k_gemm_f32<256, 384><<<32, 256, 0, stream>>>(tok_bf, outer_bfw, u_f);
  // pair output
  k_pair<<<8192, 256, 0, stream>>>(tpf, W_pairin, u_f, pair_out);
}